// Round 7
// baseline (285.130 us; speedup 1.0000x reference)
//
#include <hip/hip_runtime.h>
#include <stdint.h>

#define OBS_LEN 12
#define KS 20
#define BB 2048
#define HD 128
#define MIDD 256
#define NCQ 2

// d_ws layout (bf16 elems): fragment-ordered weight copies
#define WSW_OFF  0          // whh  [8w][4gate][4q][64l][8]  = 65536
#define WSM0_OFF 65536      // mw0  [8w][2ct][4q][64l][8]    = 32768
#define WSM1_OFF 98304      // mw1  [8w][8q][64l][8]         = 32768
#define WSO_OFF  131072     // oww  [4q][64l][8]             = 2048
#define WS_ELEMS 133120     // * 2 B = 266240 bytes

using f32x4  = __attribute__((ext_vector_type(4))) float;
using bf16x8 = __attribute__((ext_vector_type(8))) short;

static __device__ __forceinline__ short f2bf(float f){
  return __builtin_bit_cast(short, (__bf16)f);   // RNE convert
}
static __device__ __forceinline__ uint32_t pack2(float a, float b){
  return (uint32_t)(uint16_t)f2bf(a) | ((uint32_t)(uint16_t)f2bf(b) << 16);
}
static __device__ __forceinline__ float hsig(float x){
  return fminf(fmaxf(fmaf(x, 0.16666666666666666f, 0.5f), 0.f), 1.f);
}
static __device__ __forceinline__ float clip1(float x){
  return fminf(fmaxf(x, -1.f), 1.f);
}
static __device__ __forceinline__ f32x4 mm(bf16x8 a, bf16x8 b, f32x4 c){
  return __builtin_amdgcn_mfma_f32_16x16x32_bf16(a, b, c, 0, 0, 0);
}
static __device__ __forceinline__ bf16x8 ldh(const uint16_t* buf, int row, int q, int p){
  return *reinterpret_cast<const bf16x8*>(&buf[(row*HD + q*32 + p*8) ^ ((row&7)*8)]);
}
static __device__ __forceinline__ bf16x8 lda(const uint16_t* buf, int row, int q, int p){
  return *reinterpret_cast<const bf16x8*>(&buf[(row*MIDD + q*32 + p*8) ^ ((row&7)*8)]);
}

// ---------------- prep: reorder weights into MFMA fragment order ----------------
__global__ void CRMF_prep_kernel(const float* __restrict__ mw0,
                                 const float* __restrict__ mw1,
                                 const float* __restrict__ whh,
                                 const float* __restrict__ oww,
                                 uint16_t* __restrict__ ws)
{
  int f = blockIdx.x*256 + threadIdx.x;
  if (f >= 16640) return;
  bf16x8 out;
  int dst;
  if (f < 8192){                       // whh frags
    int l=f&63, q=(f>>6)&3, gate=(f>>8)&3, w=f>>10;
    int col = gate*128 + w*16 + (l&15);
    const float* s = whh + col*HD + q*32 + ((l>>4)&3)*8;
    #pragma unroll
    for (int j=0;j<8;++j) out[j] = f2bf(s[j]);
    dst = WSW_OFF + f*8;
  } else if (f < 12288){               // mw0 frags
    int ff=f-8192; int l=ff&63, q=(ff>>6)&3, ct=(ff>>8)&1, w=ff>>9;
    int col = w*32 + ct*16 + (l&15);
    int r0 = q*32 + ((l>>4)&3)*8;
    #pragma unroll
    for (int j=0;j<8;++j) out[j] = f2bf(mw0[(r0+j)*MIDD + col]);
    dst = WSM0_OFF + ff*8;
  } else if (f < 16384){               // mw1 frags
    int ff=f-12288; int l=ff&63, q=(ff>>6)&7, w=ff>>9;
    int col = w*16 + (l&15);
    int r0 = q*32 + ((l>>4)&3)*8;
    #pragma unroll
    for (int j=0;j<8;++j) out[j] = f2bf(mw1[(r0+j)*HD + col]);
    dst = WSM1_OFF + ff*8;
  } else {                             // oww frags
    int ff=f-16384; int l=ff&63, q=ff>>6;
    int ln=l&15; int r0 = q*32 + ((l>>4)&3)*8;
    #pragma unroll
    for (int j=0;j<8;++j) out[j] = (ln<NCQ) ? f2bf(oww[(r0+j)*NCQ + ln]) : (short)0;
    dst = WSO_OFF + ff*8;
  }
  *reinterpret_cast<bf16x8*>(&ws[dst]) = out;
}

// ---------------- pair runner: two independent chunks interleaved ----------------
template<bool FWS, bool HASB>
static __device__ __forceinline__ void run_pair(
    int kkA, int kkB, int b0,
    const float* __restrict__ pred,
    const float* __restrict__ mb0, const float* __restrict__ mb1,
    const float* __restrict__ mw0, const float* __restrict__ mw1,
    const uint16_t* __restrict__ ws,
    const bf16x8 (&wfrag)[4][4],
    const float (&wihA)[4], const float (&wihB)[4], const float (&biasv)[4],
    const uint16_t* ofrag, float obv,
    uint16_t (*hA)[32*HD], uint16_t (*hB)[32*HD],
    uint16_t* abA, uint16_t* abB,
    const float2 (&xbuf)[OBS_LEN][32],
    float* __restrict__ outp,
    int tid, int w, int l, int p, int ln, int wofs, bool w7)
{
  __syncthreads();   // WAR vs previous pair's readers of h/ab buffers

  // ---- stage h0 for A (and B) ----
  {
    const float* srcA = pred + ((size_t)(kkA*BB + b0))*HD;
    #pragma unroll
    for (int it=0; it<2; ++it){
      int u = tid + it*512;
      int row = u >> 5, c4 = (u & 31)*4;
      float4 v = *reinterpret_cast<const float4*>(srcA + row*HD + c4);
      int e = (row*HD + c4) ^ ((row&7)*8);
      *reinterpret_cast<uint32_t*>(&hA[0][e])   = pack2(v.x, v.y);
      *reinterpret_cast<uint32_t*>(&hA[0][e+2]) = pack2(v.z, v.w);
    }
    if constexpr (HASB){
      const float* srcB = pred + ((size_t)(kkB*BB + b0))*HD;
      #pragma unroll
      for (int it=0; it<2; ++it){
        int u = tid + it*512;
        int row = u >> 5, c4 = (u & 31)*4;
        float4 v = *reinterpret_cast<const float4*>(srcB + row*HD + c4);
        int e = (row*HD + c4) ^ ((row&7)*8);
        *reinterpret_cast<uint32_t*>(&hB[0][e])   = pack2(v.x, v.y);
        *reinterpret_cast<uint32_t*>(&hB[0][e+2]) = pack2(v.z, v.w);
      }
    }
  }
  __syncthreads();

  // ---- MLP GEMM1: [32,128] @ map_w0 -> [32,256]; 32 cols/wave ----
  {
    f32x4 a1A[2][2], a1B[2][2];
    #pragma unroll
    for (int ct=0; ct<2; ++ct){
      float mb = mb0[w*32 + ct*16 + ln];
      f32x4 v = {mb,mb,mb,mb};
      a1A[0][ct]=v; a1A[1][ct]=v;
      if constexpr (HASB){ a1B[0][ct]=v; a1B[1][ct]=v; }
    }
    #pragma unroll
    for (int q=0; q<4; ++q){
      bf16x8 aA0 = ldh(hA[0], ln, q, p), aA1 = ldh(hA[0], 16+ln, q, p);
      bf16x8 aB0, aB1;
      if constexpr (HASB){ aB0 = ldh(hB[0], ln, q, p); aB1 = ldh(hB[0], 16+ln, q, p); }
      #pragma unroll
      for (int ct=0; ct<2; ++ct){
        bf16x8 wf;
        if constexpr (FWS){
          wf = *reinterpret_cast<const bf16x8*>(&ws[WSM0_OFF + (((w*2+ct)*4+q)*64 + l)*8]);
        } else {
          #pragma unroll
          for (int j=0; j<8; ++j)
            wf[j] = f2bf(mw0[(q*32+p*8+j)*MIDD + (w*32 + ct*16 + ln)]);
        }
        a1A[0][ct] = mm(aA0, wf, a1A[0][ct]);
        a1A[1][ct] = mm(aA1, wf, a1A[1][ct]);
        if constexpr (HASB){
          a1B[0][ct] = mm(aB0, wf, a1B[0][ct]);
          a1B[1][ct] = mm(aB1, wf, a1B[1][ct]);
        }
      }
    }
    #pragma unroll
    for (int rt=0; rt<2; ++rt)
    #pragma unroll
    for (int ct=0; ct<2; ++ct)
    #pragma unroll
    for (int r=0; r<4; ++r){
      int row = rt*16 + p*4 + r;
      int e = (row*MIDD + w*32 + ct*16 + ln) ^ ((row&7)*8);
      float vA = a1A[rt][ct][r];
      abA[e] = (uint16_t)f2bf(vA>0.f ? vA : 0.01f*vA);
      if constexpr (HASB){
        float vB = a1B[rt][ct][r];
        abB[e] = (uint16_t)f2bf(vB>0.f ? vB : 0.01f*vB);
      }
    }
  }
  __syncthreads();

  // ---- MLP GEMM2: [32,256] @ map_w1 -> h_init; 16 cols/wave ----
  float cA[2][4], cB[2][4];
  {
    f32x4 a2A[2], a2B[2];
    float mb = mb1[wofs + ln];
    f32x4 v = {mb,mb,mb,mb};
    a2A[0]=v; a2A[1]=v;
    if constexpr (HASB){ a2B[0]=v; a2B[1]=v; }
    #pragma unroll
    for (int q=0; q<8; ++q){
      bf16x8 aA0 = lda(abA, ln, q, p), aA1 = lda(abA, 16+ln, q, p);
      bf16x8 aB0, aB1;
      if constexpr (HASB){ aB0 = lda(abB, ln, q, p); aB1 = lda(abB, 16+ln, q, p); }
      bf16x8 wf;
      if constexpr (FWS){
        wf = *reinterpret_cast<const bf16x8*>(&ws[WSM1_OFF + ((w*8+q)*64 + l)*8]);
      } else {
        #pragma unroll
        for (int j=0; j<8; ++j)
          wf[j] = f2bf(mw1[(q*32+p*8+j)*HD + wofs + ln]);
      }
      a2A[0] = mm(aA0, wf, a2A[0]);
      a2A[1] = mm(aA1, wf, a2A[1]);
      if constexpr (HASB){
        a2B[0] = mm(aB0, wf, a2B[0]);
        a2B[1] = mm(aB1, wf, a2B[1]);
      }
    }
    #pragma unroll
    for (int rt=0; rt<2; ++rt)
    #pragma unroll
    for (int r=0; r<4; ++r){
      int row = rt*16 + p*4 + r;
      int e = (row*HD + wofs + ln) ^ ((row&7)*8);
      hA[0][e] = (uint16_t)f2bf(a2A[rt][r]);
      cA[rt][r] = 0.f;
      if constexpr (HASB){
        hB[0][e] = (uint16_t)f2bf(a2B[rt][r]);
        cB[rt][r] = 0.f;
      }
    }
  }
  __syncthreads();

  // ---- 12 recurrent steps, double-buffered h, ONE barrier/step ----
  #pragma unroll 1
  for (int t=0; t<OBS_LEN; ++t){
    const int cur = t & 1, nxt = cur ^ 1;
    f32x4 accA[2][4], accB[2][4];
    #pragma unroll
    for (int rt=0; rt<2; ++rt){
      #pragma unroll
      for (int r=0; r<4; ++r){
        float2 xv = xbuf[t][rt*16 + p*4 + r];
        #pragma unroll
        for (int gate=0; gate<4; ++gate){
          float a = fmaf(xv.x, wihA[gate], fmaf(xv.y, wihB[gate], biasv[gate]));
          accA[rt][gate][r] = a;
          if constexpr (HASB) accB[rt][gate][r] = a;
        }
      }
    }
    f32x4 a8A[2], a8B[2];
    if (w7 && t>0){
      f32x4 v={obv,obv,obv,obv};
      a8A[0]=v; a8A[1]=v;
      if constexpr (HASB){ a8B[0]=v; a8B[1]=v; }
    }
    #pragma unroll
    for (int q=0; q<4; ++q){
      bf16x8 aA0 = ldh(hA[cur], ln, q, p), aA1 = ldh(hA[cur], 16+ln, q, p);
      bf16x8 aB0, aB1;
      if constexpr (HASB){ aB0 = ldh(hB[cur], ln, q, p); aB1 = ldh(hB[cur], 16+ln, q, p); }
      #pragma unroll
      for (int gate=0; gate<4; ++gate){
        accA[0][gate] = mm(aA0, wfrag[gate][q], accA[0][gate]);
        accA[1][gate] = mm(aA1, wfrag[gate][q], accA[1][gate]);
        if constexpr (HASB){
          accB[0][gate] = mm(aB0, wfrag[gate][q], accB[0][gate]);
          accB[1][gate] = mm(aB1, wfrag[gate][q], accB[1][gate]);
        }
      }
      if (w7 && t>0){
        bf16x8 of = *reinterpret_cast<const bf16x8*>(&ofrag[(q*64 + l)*8]);
        a8A[0] = mm(aA0, of, a8A[0]);
        a8A[1] = mm(aA1, of, a8A[1]);
        if constexpr (HASB){
          a8B[0] = mm(aB0, of, a8B[0]);
          a8B[1] = mm(aB1, of, a8B[1]);
        }
      }
    }
    if (w7 && t>0 && ln<NCQ){
      #pragma unroll
      for (int rt=0; rt<2; ++rt)
      #pragma unroll
      for (int r=0; r<4; ++r){
        int cell = rt*16 + p*4 + r;
        outp[(((size_t)(t-1)*KS + kkA)*BB + b0 + cell)*NCQ + ln] = a8A[rt][r];
        if constexpr (HASB)
          outp[(((size_t)(t-1)*KS + kkB)*BB + b0 + cell)*NCQ + ln] = a8B[rt][r];
      }
    }
    #pragma unroll
    for (int rt=0; rt<2; ++rt)
    #pragma unroll
    for (int r=0; r<4; ++r){
      int row = rt*16 + p*4 + r;
      int e = (row*HD + wofs + ln) ^ ((row&7)*8);
      {
        float iv = hsig(accA[rt][0][r]);
        float fv = hsig(accA[rt][1][r]);
        float gv = clip1(accA[rt][2][r]);
        float ov = hsig(accA[rt][3][r]);
        float cv = fmaf(fv, cA[rt][r], iv*gv);
        cA[rt][r] = cv;
        hA[nxt][e] = (uint16_t)f2bf(ov * clip1(cv));
      }
      if constexpr (HASB){
        float iv = hsig(accB[rt][0][r]);
        float fv = hsig(accB[rt][1][r]);
        float gv = clip1(accB[rt][2][r]);
        float ov = hsig(accB[rt][3][r]);
        float cv = fmaf(fv, cB[rt][r], iv*gv);
        cB[rt][r] = cv;
        hB[nxt][e] = (uint16_t)f2bf(ov * clip1(cv));
      }
    }
    __syncthreads();   // h[nxt] visible; WAR on h[cur] is one step (one barrier) away
  }

  // ---- final out_11 (final h is in dbuf 0) ----
  if (w7){
    f32x4 oA0 = {obv,obv,obv,obv}, oA1 = oA0, oB0 = oA0, oB1 = oA0;
    #pragma unroll
    for (int q=0; q<4; ++q){
      bf16x8 of = *reinterpret_cast<const bf16x8*>(&ofrag[(q*64 + l)*8]);
      bf16x8 aA0 = ldh(hA[0], ln, q, p), aA1 = ldh(hA[0], 16+ln, q, p);
      oA0 = mm(aA0, of, oA0);
      oA1 = mm(aA1, of, oA1);
      if constexpr (HASB){
        bf16x8 aB0 = ldh(hB[0], ln, q, p), aB1 = ldh(hB[0], 16+ln, q, p);
        oB0 = mm(aB0, of, oB0);
        oB1 = mm(aB1, of, oB1);
      }
    }
    if (ln < NCQ){
      #pragma unroll
      for (int r=0; r<4; ++r){
        outp[(((size_t)11*KS + kkA)*BB + b0 +      (p*4+r))*NCQ + ln] = oA0[r];
        outp[(((size_t)11*KS + kkA)*BB + b0 + 16 + (p*4+r))*NCQ + ln] = oA1[r];
        if constexpr (HASB){
          outp[(((size_t)11*KS + kkB)*BB + b0 +      (p*4+r))*NCQ + ln] = oB0[r];
          outp[(((size_t)11*KS + kkB)*BB + b0 + 16 + (p*4+r))*NCQ + ln] = oB1[r];
        }
      }
    }
  }
}

// ---------------- main kernel ----------------
template<bool FWS>
__global__ __launch_bounds__(512, 2)
void CRMF_35296041239144_kernel(
    const float* __restrict__ obs,  const float* __restrict__ pred,
    const float* __restrict__ mw0,  const float* __restrict__ mb0,
    const float* __restrict__ mw1,  const float* __restrict__ mb1,
    const float* __restrict__ wih,  const float* __restrict__ whh,
    const float* __restrict__ bih,  const float* __restrict__ bhh,
    const float* __restrict__ oww,  const float* __restrict__ obb,
    const uint16_t* __restrict__ ws,
    float* __restrict__ outp)
{
  __shared__ __align__(16) uint16_t hbufA[2][32*HD];
  __shared__ __align__(16) uint16_t hbufB[2][32*HD];
  __shared__ __align__(16) uint16_t abufA[32*MIDD];
  __shared__ __align__(16) uint16_t abufB[32*MIDD];
  __shared__ __align__(16) uint16_t ofrag[4*64*8];
  __shared__ float2 xbuf[OBS_LEN][32];

  const int tid = threadIdx.x;
  const int w   = tid >> 6;
  const int l   = tid & 63;
  const int p   = (tid >> 4) & 3;
  const int ln  = tid & 15;
  const int wofs = w * 16;
  const bool w7 = (w == 7);

  const int b     = blockIdx.x;      // 256 blocks, 1 per CU
  const int b0    = (b & 63) * 32;
  const int kslot = b >> 6;          // 0..3 ; kk = kslot*5 + c

  // shifted obs
  if (tid < OBS_LEN*32){
    int t = tid >> 5, cc = tid & 31;
    int st = t ? (t-1) : 0;
    const float* pp = obs + ((size_t)st*BB + b0 + cc)*3;
    xbuf[t][cc] = make_float2(pp[0], pp[1]);
  }
  // out_w fragments -> LDS
  if (tid < 256){
    if constexpr (FWS){
      *reinterpret_cast<bf16x8*>(&ofrag[tid*8]) =
          *reinterpret_cast<const bf16x8*>(&ws[WSO_OFF + tid*8]);
    } else {
      int q = tid >> 6, ll = tid & 63;
      int lln = ll & 15, pp2 = (ll >> 4) & 3;
      bf16x8 wf;
      #pragma unroll
      for (int j=0; j<8; ++j)
        wf[j] = (lln < NCQ) ? f2bf(oww[(q*32+pp2*8+j)*NCQ + lln]) : (short)0;
      *reinterpret_cast<bf16x8*>(&ofrag[tid*8]) = wf;
    }
  }
  const float obv = (ln < NCQ) ? obb[ln] : 0.f;

  // w_hh fragments -> registers (64 VGPR)
  bf16x8 wfrag[4][4];
  #pragma unroll
  for (int gate=0; gate<4; ++gate){
    #pragma unroll
    for (int q=0; q<4; ++q){
      if constexpr (FWS){
        wfrag[gate][q] = *reinterpret_cast<const bf16x8*>(
            &ws[WSW_OFF + (((w*4+gate)*4+q)*64 + l)*8]);
      } else {
        int col = gate*128 + wofs + ln;
        const float* s = whh + col*HD + q*32 + p*8;
        float4 f0 = *reinterpret_cast<const float4*>(s);
        float4 f1 = *reinterpret_cast<const float4*>(s+4);
        bf16x8 wf;
        wf[0]=f2bf(f0.x); wf[1]=f2bf(f0.y); wf[2]=f2bf(f0.z); wf[3]=f2bf(f0.w);
        wf[4]=f2bf(f1.x); wf[5]=f2bf(f1.y); wf[6]=f2bf(f1.z); wf[7]=f2bf(f1.w);
        wfrag[gate][q] = wf;
      }
    }
  }
  float wihA[4], wihB[4], biasv[4];
  #pragma unroll
  for (int gate=0; gate<4; ++gate){
    int col = gate*128 + wofs + ln;
    wihA[gate]  = wih[col*2];
    wihB[gate]  = wih[col*2+1];
    biasv[gate] = bih[col] + bhh[col];
  }

  // 5 chunks = 2 interleaved pairs + 1 solo
  run_pair<FWS,true >(kslot*5+0, kslot*5+1, b0, pred, mb0, mb1, mw0, mw1, ws,
                      wfrag, wihA, wihB, biasv, ofrag, obv,
                      hbufA, hbufB, abufA, abufB, xbuf, outp,
                      tid, w, l, p, ln, wofs, w7);
  run_pair<FWS,true >(kslot*5+2, kslot*5+3, b0, pred, mb0, mb1, mw0, mw1, ws,
                      wfrag, wihA, wihB, biasv, ofrag, obv,
                      hbufA, hbufB, abufA, abufB, xbuf, outp,
                      tid, w, l, p, ln, wofs, w7);
  run_pair<FWS,false>(kslot*5+4, kslot*5+4, b0, pred, mb0, mb1, mw0, mw1, ws,
                      wfrag, wihA, wihB, biasv, ofrag, obv,
                      hbufA, hbufB, abufA, abufB, xbuf, outp,
                      tid, w, l, p, ln, wofs, w7);
}

extern "C" void kernel_launch(void* const* d_in, const int* in_sizes, int n_in,
                              void* d_out, int out_size, void* d_ws, size_t ws_size,
                              hipStream_t stream) {
  (void)in_sizes; (void)n_in; (void)out_size;
  const float* obs  = (const float*)d_in[0];
  const float* pred = (const float*)d_in[1];
  const float* mw0  = (const float*)d_in[2];
  const float* mb0  = (const float*)d_in[3];
  const float* mw1  = (const float*)d_in[4];
  const float* mb1  = (const float*)d_in[5];
  const float* wih  = (const float*)d_in[6];
  const float* whh  = (const float*)d_in[7];
  const float* bih  = (const float*)d_in[8];
  const float* bhh  = (const float*)d_in[9];
  const float* oww  = (const float*)d_in[10];
  const float* obb  = (const float*)d_in[11];
  float* outp = (float*)d_out;

  if (ws_size >= (size_t)WS_ELEMS * sizeof(uint16_t)){
    uint16_t* ws = (uint16_t*)d_ws;
    CRMF_prep_kernel<<<dim3(65), dim3(256), 0, stream>>>(mw0, mw1, whh, oww, ws);
    CRMF_35296041239144_kernel<true><<<dim3(256), dim3(512), 0, stream>>>(
        obs, pred, mw0, mb0, mw1, mb1, wih, whh, bih, bhh, oww, obb,
        (const uint16_t*)ws, outp);
  } else {
    CRMF_35296041239144_kernel<false><<<dim3(256), dim3(512), 0, stream>>>(
        obs, pred, mw0, mb0, mw1, mb1, wih, whh, bih, bhh, oww, obb,
        (const uint16_t*)nullptr, outp);
  }
}

// Round 8
// 284.182 us; speedup vs baseline: 1.0033x; 1.0033x over previous
//
#include <hip/hip_runtime.h>
#include <stdint.h>

#define OBS_LEN 12
#define KS 20
#define BB 2048
#define HD 128
#define MIDD 256
#define NCQ 2

// d_ws layout (bf16 elems): fragment-ordered weight copies
#define WSW_OFF  0          // whh  [8w][4gate][4q][64l][8]  = 65536
#define WSM0_OFF 65536      // mw0  [8w][2ct][4q][64l][8]    = 32768
#define WSM1_OFF 98304      // mw1  [8w][8q][64l][8]         = 32768
#define WSO_OFF  131072     // oww  [4q][64l][8]             = 2048
#define WS_ELEMS 133120     // * 2 B = 266240 bytes

using f32x4  = __attribute__((ext_vector_type(4))) float;
using bf16x8 = __attribute__((ext_vector_type(8))) short;

static __device__ __forceinline__ short f2bf(float f){
  return __builtin_bit_cast(short, (__bf16)f);   // RNE convert
}
static __device__ __forceinline__ uint32_t pack2(float a, float b){
  return (uint32_t)(uint16_t)f2bf(a) | ((uint32_t)(uint16_t)f2bf(b) << 16);
}
static __device__ __forceinline__ float hsig(float x){
  return fminf(fmaxf(fmaf(x, 0.16666666666666666f, 0.5f), 0.f), 1.f);
}
static __device__ __forceinline__ float clip1(float x){
  return fminf(fmaxf(x, -1.f), 1.f);
}
static __device__ __forceinline__ f32x4 mm(bf16x8 a, bf16x8 b, f32x4 c){
  return __builtin_amdgcn_mfma_f32_16x16x32_bf16(a, b, c, 0, 0, 0);
}
static __device__ __forceinline__ bf16x8 ldh(const uint16_t* buf, int row, int q, int p){
  return *reinterpret_cast<const bf16x8*>(&buf[(row*HD + q*32 + p*8) ^ ((row&7)*8)]);
}
static __device__ __forceinline__ bf16x8 lda(const uint16_t* buf, int row, int q, int p){
  return *reinterpret_cast<const bf16x8*>(&buf[(row*MIDD + q*32 + p*8) ^ ((row&7)*8)]);
}

// ---------------- prep: reorder weights into MFMA fragment order ----------------
__global__ void CRMF_prep_kernel(const float* __restrict__ mw0,
                                 const float* __restrict__ mw1,
                                 const float* __restrict__ whh,
                                 const float* __restrict__ oww,
                                 uint16_t* __restrict__ ws)
{
  int f = blockIdx.x*256 + threadIdx.x;
  if (f >= 16640) return;
  bf16x8 out;
  int dst;
  if (f < 8192){                       // whh frags
    int l=f&63, q=(f>>6)&3, gate=(f>>8)&3, w=f>>10;
    int col = gate*128 + w*16 + (l&15);
    const float* s = whh + col*HD + q*32 + ((l>>4)&3)*8;
    #pragma unroll
    for (int j=0;j<8;++j) out[j] = f2bf(s[j]);
    dst = WSW_OFF + f*8;
  } else if (f < 12288){               // mw0 frags
    int ff=f-8192; int l=ff&63, q=(ff>>6)&3, ct=(ff>>8)&1, w=ff>>9;
    int col = w*32 + ct*16 + (l&15);
    int r0 = q*32 + ((l>>4)&3)*8;
    #pragma unroll
    for (int j=0;j<8;++j) out[j] = f2bf(mw0[(r0+j)*MIDD + col]);
    dst = WSM0_OFF + ff*8;
  } else if (f < 16384){               // mw1 frags
    int ff=f-12288; int l=ff&63, q=(ff>>6)&7, w=ff>>9;
    int col = w*16 + (l&15);
    int r0 = q*32 + ((l>>4)&3)*8;
    #pragma unroll
    for (int j=0;j<8;++j) out[j] = f2bf(mw1[(r0+j)*HD + col]);
    dst = WSM1_OFF + ff*8;
  } else {                             // oww frags
    int ff=f-16384; int l=ff&63, q=ff>>6;
    int ln=l&15; int r0 = q*32 + ((l>>4)&3)*8;
    #pragma unroll
    for (int j=0;j<8;++j) out[j] = (ln<NCQ) ? f2bf(oww[(r0+j)*NCQ + ln]) : (short)0;
    dst = WSO_OFF + ff*8;
  }
  *reinterpret_cast<bf16x8*>(&ws[dst]) = out;
}

// ---------------- main kernel: 1024 thr = 16 waves = 2 chunks ----------------
template<bool FWS>
__global__ __launch_bounds__(1024, 1)
void CRMF_35296041239144_kernel(
    const float* __restrict__ obs,  const float* __restrict__ pred,
    const float* __restrict__ mw0,  const float* __restrict__ mb0,
    const float* __restrict__ mw1,  const float* __restrict__ mb1,
    const float* __restrict__ wih,  const float* __restrict__ whh,
    const float* __restrict__ bih,  const float* __restrict__ bhh,
    const float* __restrict__ oww,  const float* __restrict__ obb,
    const uint16_t* __restrict__ ws,
    float* __restrict__ outp)
{
  // 128 KB: whh fragments during steps; aliased as 2x MLP activation bufs
  __shared__ __align__(16) uint16_t wlds[65536];
  __shared__ __align__(16) uint16_t hb[2][32*HD];    // 16 KB: per-chunk h state
  __shared__ __align__(16) uint16_t ofrag[4*64*8];   // 4 KB out_w B-fragments
  __shared__ float2 xbuf[OBS_LEN][32];               // 3 KB shifted obs

  const int tid = threadIdx.x;
  const int g   = tid >> 9;          // chunk half 0/1
  const int lt  = tid & 511;         // tid within half
  const int cw  = (tid >> 6) & 7;    // chunk-local wave 0..7
  const int l   = tid & 63;
  const int p   = (tid >> 4) & 3;
  const int ln  = tid & 15;
  const int wofs = cw * 16;          // wave's 16-hd slice
  const bool wOut = (cw == 7);

  const int b     = blockIdx.x;      // 256 blocks, 1 per CU
  const int b0    = (b & 63) * 32;
  const int kslot = b >> 6;          // 0..3

  // shifted obs
  if (tid < OBS_LEN*32){
    int t = tid >> 5, cc = tid & 31;
    int st = t ? (t-1) : 0;
    const float* pp = obs + ((size_t)st*BB + b0 + cc)*3;
    xbuf[t][cc] = make_float2(pp[0], pp[1]);
  }
  // out_w fragments -> LDS
  if (tid < 256){
    if constexpr (FWS){
      *reinterpret_cast<bf16x8*>(&ofrag[tid*8]) =
          *reinterpret_cast<const bf16x8*>(&ws[WSO_OFF + tid*8]);
    } else {
      int q = tid >> 6, ll = tid & 63;
      int lln = ll & 15, pp2 = (ll >> 4) & 3;
      bf16x8 wf;
      #pragma unroll
      for (int j=0; j<8; ++j)
        wf[j] = (lln < NCQ) ? f2bf(oww[(q*32+pp2*8+j)*NCQ + lln]) : (short)0;
      *reinterpret_cast<bf16x8*>(&ofrag[tid*8]) = wf;
    }
  }
  const float obv = (ln < NCQ) ? obb[ln] : 0.f;

  // per-wave x-projection scalars
  float wihA[4], wihB[4], biasv[4];
  #pragma unroll
  for (int gate=0; gate<4; ++gate){
    int col = gate*128 + wofs + ln;
    wihA[gate]  = wih[col*2];
    wihB[gate]  = wih[col*2+1];
    biasv[gate] = bih[col] + bhh[col];
  }

  uint16_t* ab = wlds + g*8192;      // chunk's MLP activations (aliases whh region)

  // ---- 3 iterations x 2 chunks: (0,1) (2,3) (4,4-dup) ----
  #pragma unroll 1
  for (int iter=0; iter<3; ++iter){
    const int kk = kslot*5 + ((iter<2) ? iter*2 + g : 4);

    __syncthreads();                 // WAR: previous iteration's readers done

    // stage h0 for this chunk (512 threads per chunk)
    {
      const float* src = pred + ((size_t)(kk*BB + b0))*HD;
      #pragma unroll
      for (int it=0; it<2; ++it){
        int u = lt + it*512;
        int row = u >> 5, c4 = (u & 31)*4;
        float4 v = *reinterpret_cast<const float4*>(src + row*HD + c4);
        int e = (row*HD + c4) ^ ((row&7)*8);
        *reinterpret_cast<uint32_t*>(&hb[g][e])   = pack2(v.x, v.y);
        *reinterpret_cast<uint32_t*>(&hb[g][e+2]) = pack2(v.z, v.w);
      }
    }
    __syncthreads();

    // ---- MLP GEMM1: [32,128] @ map_w0 -> [32,256]; 32 cols/wave ----
    {
      f32x4 acc1[2][2];
      #pragma unroll
      for (int ct=0; ct<2; ++ct){
        float mb = mb0[cw*32 + ct*16 + ln];
        f32x4 v = {mb,mb,mb,mb};
        acc1[0][ct]=v; acc1[1][ct]=v;
      }
      #pragma unroll
      for (int q=0; q<4; ++q){
        bf16x8 af0 = ldh(hb[g], ln, q, p), af1 = ldh(hb[g], 16+ln, q, p);
        #pragma unroll
        for (int ct=0; ct<2; ++ct){
          bf16x8 wf;
          if constexpr (FWS){
            wf = *reinterpret_cast<const bf16x8*>(&ws[WSM0_OFF + (((cw*2+ct)*4+q)*64 + l)*8]);
          } else {
            #pragma unroll
            for (int j=0; j<8; ++j)
              wf[j] = f2bf(mw0[(q*32+p*8+j)*MIDD + (cw*32 + ct*16 + ln)]);
          }
          acc1[0][ct] = mm(af0, wf, acc1[0][ct]);
          acc1[1][ct] = mm(af1, wf, acc1[1][ct]);
        }
      }
      #pragma unroll
      for (int rt=0; rt<2; ++rt)
      #pragma unroll
      for (int ct=0; ct<2; ++ct)
      #pragma unroll
      for (int r=0; r<4; ++r){
        float v = acc1[rt][ct][r];
        v = (v>0.f)? v : 0.01f*v;
        int row = rt*16 + p*4 + r;
        ab[(row*MIDD + cw*32 + ct*16 + ln) ^ ((row&7)*8)] = (uint16_t)f2bf(v);
      }
    }
    __syncthreads();

    // ---- MLP GEMM2: [32,256] @ map_w1 -> h_init; 16 cols/wave ----
    float c_[2][4];
    {
      f32x4 acc2[2];
      float mb = mb1[wofs + ln];
      f32x4 v = {mb,mb,mb,mb};
      acc2[0]=v; acc2[1]=v;
      #pragma unroll
      for (int q=0; q<8; ++q){
        bf16x8 af0 = lda(ab, ln, q, p), af1 = lda(ab, 16+ln, q, p);
        bf16x8 wf;
        if constexpr (FWS){
          wf = *reinterpret_cast<const bf16x8*>(&ws[WSM1_OFF + ((cw*8+q)*64 + l)*8]);
        } else {
          #pragma unroll
          for (int j=0; j<8; ++j)
            wf[j] = f2bf(mw1[(q*32+p*8+j)*HD + wofs + ln]);
        }
        acc2[0] = mm(af0, wf, acc2[0]);
        acc2[1] = mm(af1, wf, acc2[1]);
      }
      #pragma unroll
      for (int rt=0; rt<2; ++rt)
      #pragma unroll
      for (int r=0; r<4; ++r){
        int row = rt*16 + p*4 + r;
        hb[g][(row*HD + wofs + ln) ^ ((row&7)*8)] = (uint16_t)f2bf(acc2[rt][r]);
        c_[rt][r] = 0.f;
      }
    }
    __syncthreads();                 // h_init visible; all abuf reads done

    // ---- stage whh fragments into wlds (overwrites abuf region) ----
    if constexpr (FWS){
      #pragma unroll
      for (int it=0; it<8; ++it){
        int idx = (tid + it*1024)*8;
        *reinterpret_cast<bf16x8*>(&wlds[idx]) =
            *reinterpret_cast<const bf16x8*>(&ws[WSW_OFF + idx]);
      }
    } else {
      #pragma unroll
      for (int it=0; it<8; ++it){
        int s = tid + it*1024;                 // frag slot 0..8191
        int sl=s&63, sq=(s>>6)&3, sg=(s>>8)&3, sw=s>>10;
        int col = sg*128 + sw*16 + (sl&15);
        const float* sp = whh + col*HD + sq*32 + ((sl>>4)&3)*8;
        bf16x8 wf;
        #pragma unroll
        for (int j=0;j<8;++j) wf[j] = f2bf(sp[j]);
        *reinterpret_cast<bf16x8*>(&wlds[s*8]) = wf;
      }
    }
    __syncthreads();                 // whh frags ready

    // ---- 12 recurrent steps; wfrag read JIT from LDS ----
    #pragma unroll 1
    for (int t=0; t<OBS_LEN; ++t){
      f32x4 acc[2][4];
      #pragma unroll
      for (int rt=0; rt<2; ++rt){
        #pragma unroll
        for (int r=0; r<4; ++r){
          float2 xv = xbuf[t][rt*16 + p*4 + r];
          #pragma unroll
          for (int gate=0; gate<4; ++gate)
            acc[rt][gate][r] = fmaf(xv.x, wihA[gate], fmaf(xv.y, wihB[gate], biasv[gate]));
        }
      }
      f32x4 a8[2];
      if (wOut && t>0){ f32x4 v={obv,obv,obv,obv}; a8[0]=v; a8[1]=v; }
      #pragma unroll
      for (int q=0; q<4; ++q){
        bf16x8 af0 = ldh(hb[g], ln, q, p), af1 = ldh(hb[g], 16+ln, q, p);
        #pragma unroll
        for (int gate=0; gate<4; ++gate){
          bf16x8 wf = *reinterpret_cast<const bf16x8*>(
              &wlds[(((cw*4+gate)*4+q)*64 + l)*8]);
          acc[0][gate] = mm(af0, wf, acc[0][gate]);
          acc[1][gate] = mm(af1, wf, acc[1][gate]);
        }
        if (wOut && t>0){
          bf16x8 of = *reinterpret_cast<const bf16x8*>(&ofrag[(q*64 + l)*8]);
          a8[0] = mm(af0, of, a8[0]);
          a8[1] = mm(af1, of, a8[1]);
        }
      }
      if (wOut && t>0 && ln<NCQ){
        #pragma unroll
        for (int rt=0; rt<2; ++rt)
        #pragma unroll
        for (int r=0; r<4; ++r){
          int cell = rt*16 + p*4 + r;
          outp[(((size_t)(t-1)*KS + kk)*BB + b0 + cell)*NCQ + ln] = a8[rt][r];
        }
      }
      __syncthreads();               // all hb reads done
      #pragma unroll
      for (int rt=0; rt<2; ++rt)
      #pragma unroll
      for (int r=0; r<4; ++r){
        float iv = hsig(acc[rt][0][r]);
        float fv = hsig(acc[rt][1][r]);
        float gv = clip1(acc[rt][2][r]);
        float ov = hsig(acc[rt][3][r]);
        float cv = fmaf(fv, c_[rt][r], iv*gv);
        c_[rt][r] = cv;
        int row = rt*16 + p*4 + r;
        hb[g][(row*HD + wofs + ln) ^ ((row&7)*8)] = (uint16_t)f2bf(ov * clip1(cv));
      }
      __syncthreads();               // new h visible
    }

    // ---- final out_11 = h_12 @ out_w + out_b ----
    if (wOut){
      f32x4 o0 = {obv,obv,obv,obv}, o1 = o0;
      #pragma unroll
      for (int q=0; q<4; ++q){
        bf16x8 af0 = ldh(hb[g], ln, q, p), af1 = ldh(hb[g], 16+ln, q, p);
        bf16x8 of = *reinterpret_cast<const bf16x8*>(&ofrag[(q*64 + l)*8]);
        o0 = mm(af0, of, o0);
        o1 = mm(af1, of, o1);
      }
      if (ln < NCQ){
        #pragma unroll
        for (int r=0; r<4; ++r){
          outp[(((size_t)11*KS + kk)*BB + b0 +      (p*4+r))*NCQ + ln] = o0[r];
          outp[(((size_t)11*KS + kk)*BB + b0 + 16 + (p*4+r))*NCQ + ln] = o1[r];
        }
      }
    }
  }
}

extern "C" void kernel_launch(void* const* d_in, const int* in_sizes, int n_in,
                              void* d_out, int out_size, void* d_ws, size_t ws_size,
                              hipStream_t stream) {
  (void)in_sizes; (void)n_in; (void)out_size;
  const float* obs  = (const float*)d_in[0];
  const float* pred = (const float*)d_in[1];
  const float* mw0  = (const float*)d_in[2];
  const float* mb0  = (const float*)d_in[3];
  const float* mw1  = (const float*)d_in[4];
  const float* mb1  = (const float*)d_in[5];
  const float* wih  = (const float*)d_in[6];
  const float* whh  = (const float*)d_in[7];
  const float* bih  = (const float*)d_in[8];
  const float* bhh  = (const float*)d_in[9];
  const float* oww  = (const float*)d_in[10];
  const float* obb  = (const float*)d_in[11];
  float* outp = (float*)d_out;

  if (ws_size >= (size_t)WS_ELEMS * sizeof(uint16_t)){
    uint16_t* ws = (uint16_t*)d_ws;
    CRMF_prep_kernel<<<dim3(65), dim3(256), 0, stream>>>(mw0, mw1, whh, oww, ws);
    CRMF_35296041239144_kernel<true><<<dim3(256), dim3(1024), 0, stream>>>(
        obs, pred, mw0, mb0, mw1, mb1, wih, whh, bih, bhh, oww, obb,
        (const uint16_t*)ws, outp);
  } else {
    CRMF_35296041239144_kernel<false><<<dim3(256), dim3(1024), 0, stream>>>(
        obs, pred, mw0, mb0, mw1, mb1, wih, whh, bih, bhh, oww, obb,
        (const uint16_t*)nullptr, outp);
  }
}